// Round 4
// baseline (109.068 us; speedup 1.0000x reference)
//
#include <hip/hip_runtime.h>
#include <hip/hip_bf16.h>

#define B_ 512
#define C_ 22
#define TIN 1001
#define K_ 40
#define KS_ 25
#define TO 976
#define P_ 100
#define NW 9
#define NOUT 4
#define FCIN 360
#define NBLK 512

#define XTR 1056                 /* XT rows (need 0..1047) */
#define LDS_TOTAL (XTR * 64)     /* 67584 B */
#define NPAD 48                  /* padded filter count */
#define WB_ELEM_S (KS_ * NPAD * 32) /* per-sid elements: 38400 */

typedef __attribute__((ext_vector_type(8))) short bf16x8;
typedef __attribute__((ext_vector_type(4))) float f32x4;
typedef __attribute__((ext_vector_type(4))) int i32x4;

__device__ __forceinline__ float waveReduceSum(float v) {
#pragma unroll
  for (int m = 32; m >= 1; m >>= 1) v += __shfl_xor(v, m, 64);
  return v;
}

__device__ __forceinline__ unsigned short f2bf(float f) {
  __hip_bfloat16 h = __float2bfloat16(f);
  return *reinterpret_cast<unsigned short*>(&h);
}

// W[s][n][c][j] fp32 -> WBg[s][j][n(48)][c(32)] bf16, zero-padded, no swizzle.
__global__ __launch_bounds__(192) void wconv_kernel(const float* __restrict__ W,
                                                    unsigned short* __restrict__ WBg) {
  const int s = blockIdx.x / KS_;
  const int j = blockIdx.x % KS_;
  const int n = threadIdx.x >> 2;
  const int q = threadIdx.x & 3;
  union {
    unsigned short u[8];
    i32x4 v;
  } pk;
#pragma unroll
  for (int e = 0; e < 8; ++e) {
    const int c = q * 8 + e;
    float v = 0.f;
    if (n < K_ && c < C_) v = W[(((size_t)s * K_ + n) * C_ + c) * KS_ + j];
    pk.u[e] = f2bf(v);
  }
  *(i32x4*)(WBg + ((size_t)(s * KS_ + j) * NPAD + n) * 32 + q * 8) = pk.v;
}

#define MFMA24(A, Bv)                                                          \
  do {                                                                         \
    _Pragma("unroll") for (int nt_ = 0; nt_ < 3; ++nt_) {                      \
      _Pragma("unroll") for (int m_ = 0; m_ < 8; ++m_) {                       \
        acc[m_][nt_] =                                                         \
            __builtin_amdgcn_mfma_f32_16x16x32_bf16(A[m_], Bv[nt_], acc[m_][nt_], 0, 0, 0); \
      }                                                                        \
    }                                                                          \
  } while (0)

// One block per sample. 8 waves; wave wv owns output rows [wv*128, wv*128+128).
// A from LDS (XT, 64B rows, XOR swizzle (t>>1)&3, matched store/load).
// B from global (L2-hot 48KB/sid), 3 frags (n padded to 48).
__global__ __launch_bounds__(512, 2) void conv_kernel(
    const float* __restrict__ x, const unsigned short* __restrict__ WBg,
    const float* __restrict__ bias, float* __restrict__ pooled,
    float* __restrict__ part_sum, float* __restrict__ part_sq) {
  extern __shared__ __align__(16) char sm[];
  const int b = blockIdx.x;
  const int tid = threadIdx.x;

  int s = (int)rintf(x[(size_t)b * (C_ * TIN) + (TIN - 1)] * 1e-6f) - 1;
  s = __builtin_amdgcn_readfirstlane(min(max(s, 0), 8));

  // ---- stage xT: transpose + fp32->bf16 + chunk-XOR swizzle; zero pad ----
  {
    const float* xb = x + (size_t)b * (C_ * TIN);
    for (int task = tid; task < 4 * XTR; task += 512) {
      const int q = task / XTR;          // physical 16B chunk
      const int t = task - q * XTR;      // row (coalesced along tid)
      const int lq = q ^ ((t >> 1) & 3); // logical chunk
      union {
        unsigned short u[8];
        i32x4 v;
      } pk;
#pragma unroll
      for (int e = 0; e < 8; ++e) {
        const int c = lq * 8 + e;
        float v = 0.f;
        if (c < C_ && t < TIN - 1) v = xb[c * TIN + t];
        pk.u[e] = f2bf(v);
      }
      *(i32x4*)(sm + t * 64 + q * 16) = pk.v;
    }
  }
  __syncthreads();

  const int lane = tid & 63;
  const int wv = tid >> 6;
  const int l15 = lane & 15;
  const int lg = lane >> 4;
  const int rb = wv * 128;  // wave row base
  const int tb = rb + l15;  // m=0 A-row for this lane

  const unsigned short* WBs = WBg + (size_t)s * WB_ELEM_S + (l15 * 32 + lg * 8);

  f32x4 acc[8][3];
#pragma unroll
  for (int m = 0; m < 8; ++m)
#pragma unroll
    for (int nt = 0; nt < 3; ++nt) acc[m][nt] = (f32x4){0.f, 0.f, 0.f, 0.f};

  bf16x8 A0[8], A1[8], B0[3], B1[3];

#define LDA(J, A)                                                              \
  do {                                                                         \
    const int t_ = tb + (J);                                                   \
    const char* ap_ = sm + t_ * 64 + ((lg ^ ((t_ >> 1) & 3)) << 4);            \
    _Pragma("unroll") for (int m_ = 0; m_ < 8; ++m_) {                         \
      A[m_] = *(const bf16x8*)(ap_ + m_ * 1024);                               \
    }                                                                          \
  } while (0)

#define LDB(J, Bv)                                                             \
  do {                                                                         \
    const unsigned short* bp_ = WBs + (size_t)(J)*1536;                        \
    _Pragma("unroll") for (int nt_ = 0; nt_ < 3; ++nt_) {                      \
      Bv[nt_] = *(const bf16x8*)(bp_ + nt_ * 512);                             \
    }                                                                          \
  } while (0)

  LDA(0, A0);
  LDB(0, B0);
  for (int j = 0; j < 24; j += 2) {
    LDA(j + 1, A1);
    LDB(j + 1, B1);
    MFMA24(A0, B0);
    LDA(j + 2, A0);
    LDB(j + 2, B0);
    MFMA24(A1, B1);
  }
  MFMA24(A0, B0);  // j = 24

  // ---- epilogue: bias + ELU, BN partials, pooled-window partials ----
  float bv[3];
#pragma unroll
  for (int nt = 0; nt < 3; ++nt) {
    const int k = nt * 16 + l15;
    bv[nt] = bias[s * K_ + (k < K_ ? k : 0)];
  }
  const int wlo = rb / P_;
  const int base100 = wlo * P_;
  float sY[3] = {0.f, 0.f, 0.f}, sY2[3] = {0.f, 0.f, 0.f};
  float p0[3] = {0.f, 0.f, 0.f}, p1[3] = {0.f, 0.f, 0.f}, p2[3] = {0.f, 0.f, 0.f};
#pragma unroll
  for (int m = 0; m < 8; ++m) {
#pragma unroll
    for (int i = 0; i < 4; ++i) {
      const int t = rb + m * 16 + lg * 4 + i;
      const bool valid = (t < TO);
      const bool pool = (t < NW * P_);
      const int d = t - base100;
#pragma unroll
      for (int nt = 0; nt < 3; ++nt) {
        const float v = acc[m][nt][i] + bv[nt];
        const float y = v > 0.f ? v : expm1f(v);
        if (valid) {
          sY[nt] += y;
          sY2[nt] += y * y;
          if (pool) {
            if (d < P_)
              p0[nt] += y;
            else if (d < 2 * P_)
              p1[nt] += y;
            else
              p2[nt] += y;
          }
        }
      }
    }
  }
  float* red = (float*)sm;  // overlay on XT (dead after j-loop)...
  __syncthreads();          // ...but only after ALL waves finished reading XT
#pragma unroll
  for (int nt = 0; nt < 3; ++nt) {
#pragma unroll
    for (int r = 16; r <= 32; r <<= 1) {
      p0[nt] += __shfl_xor(p0[nt], r, 64);
      p1[nt] += __shfl_xor(p1[nt], r, 64);
      p2[nt] += __shfl_xor(p2[nt], r, 64);
      sY[nt] += __shfl_xor(sY[nt], r, 64);
      sY2[nt] += __shfl_xor(sY2[nt], r, 64);
    }
    const int k = nt * 16 + l15;
    if (lane < 16 && k < K_) {
      float* pb = pooled + (size_t)b * FCIN + k * NW;
      if (p0[nt] != 0.f) atomicAdd(&pb[wlo], p0[nt]);
      if (wlo + 1 <= NW - 1 && p1[nt] != 0.f) atomicAdd(&pb[wlo + 1], p1[nt]);
      if (wlo + 2 <= NW - 1 && p2[nt] != 0.f) atomicAdd(&pb[wlo + 2], p2[nt]);
      red[k * 8 + wv] = sY[nt];
      red[K_ * 8 + k * 8 + wv] = sY2[nt];
    }
  }
  __syncthreads();
  if (tid < K_) {
    float a = 0.f, q = 0.f;
#pragma unroll
    for (int i = 0; i < 8; ++i) {
      a += red[tid * 8 + i];
      q += red[K_ * 8 + tid * 8 + i];
    }
    part_sum[(size_t)tid * NBLK + b] = a;
    part_sq[(size_t)tid * NBLK + b] = q;
  }
}

__global__ __launch_bounds__(256) void stats_kernel(
    const float* __restrict__ part_sum, const float* __restrict__ part_sq,
    const float* __restrict__ gamma, const float* __restrict__ beta,
    float* __restrict__ ss) {
  const int k = blockIdx.x;
  float s = 0.f, q = 0.f;
  for (int i = threadIdx.x; i < NBLK; i += 256) {
    s += part_sum[(size_t)k * NBLK + i];
    q += part_sq[(size_t)k * NBLK + i];
  }
  s = waveReduceSum(s);
  q = waveReduceSum(q);
  __shared__ float ls[4], lq[4];
  const int wave = threadIdx.x >> 6, lane = threadIdx.x & 63;
  if (lane == 0) {
    ls[wave] = s;
    lq[wave] = q;
  }
  __syncthreads();
  if (threadIdx.x == 0) {
    const float S = ls[0] + ls[1] + ls[2] + ls[3];
    const float Q = lq[0] + lq[1] + lq[2] + lq[3];
    const float N = (float)B_ * (float)TO;
    const float mean = S / N;
    const float var = Q / N - mean * mean;
    const float sc = gamma[k] / sqrtf(var + 1e-5f);
    ss[k] = sc;
    ss[K_ + k] = beta[k] - mean * sc;
  }
}

__global__ __launch_bounds__(256) void fc_kernel(
    const float* __restrict__ pooled, const float* __restrict__ ss,
    const float* __restrict__ fc_w, const float* __restrict__ fc_b,
    float* __restrict__ out) {
  const int bb = blockIdx.x;
  const int n = threadIdx.x >> 6;
  const int lane = threadIdx.x & 63;
  float acc = 0.f;
  for (int i = lane; i < FCIN; i += 64) {
    const int k = i / NW;
    const float y = pooled[(size_t)bb * FCIN + i] * (1.f / (float)P_) * ss[k] + ss[K_ + k];
    acc = fmaf(y, fc_w[n * FCIN + i], acc);
  }
  acc = waveReduceSum(acc);
  if (lane == 0) out[bb * NOUT + n] = acc + fc_b[n];
}

extern "C" void kernel_launch(void* const* d_in, const int* in_sizes, int n_in,
                              void* d_out, int out_size, void* d_ws, size_t ws_size,
                              hipStream_t stream) {
  const float* x = (const float*)d_in[0];
  const float* W = (const float*)d_in[1];
  const float* bias = (const float*)d_in[2];
  const float* gamma = (const float*)d_in[3];
  const float* beta = (const float*)d_in[4];
  const float* fc_w = (const float*)d_in[5];
  const float* fc_b = (const float*)d_in[6];
  float* out = (float*)d_out;

  char* ws = (char*)d_ws;
  float* pooled = (float*)ws;                             // 737280 B
  float* part_sum = (float*)(ws + 737280);                // 40*512*4 = 81920
  float* part_sq = (float*)(ws + 819200);                 // 81920
  unsigned short* WBg = (unsigned short*)(ws + 901120);   // 9*38400*2 = 691200
  float* ss = (float*)(ws + 1592320);                     // 320

  hipFuncSetAttribute((const void*)conv_kernel,
                      hipFuncAttributeMaxDynamicSharedMemorySize, LDS_TOTAL);

  hipMemsetAsync(pooled, 0, 737280, stream);
  wconv_kernel<<<9 * KS_, 192, 0, stream>>>(W, WBg);
  conv_kernel<<<NBLK, 512, LDS_TOTAL, stream>>>(x, WBg, bias, pooled, part_sum, part_sq);
  stats_kernel<<<K_, 256, 0, stream>>>(part_sum, part_sq, gamma, beta, ss);
  fc_kernel<<<B_, 256, 0, stream>>>(pooled, ss, fc_w, fc_b, out);
}

// Round 5
// 106.798 us; speedup vs baseline: 1.0213x; 1.0213x over previous
//
#include <hip/hip_runtime.h>
#include <hip/hip_bf16.h>

#define B_ 512
#define C_ 22
#define TIN 1001
#define K_ 40
#define KS_ 25
#define TO 976
#define P_ 100
#define NW 9
#define NOUT 4
#define FCIN 360

#define QROWS 280                 /* 256 out rows + 24 boundary */
#define XT_BYTES (QROWS * 64)     /* 17920 */
#define RED_OFF XT_BYTES
#define RED_BYTES (K_ * 4 * 2 * 4) /* 1280 */
#define LDS_TOTAL (RED_OFF + RED_BYTES) /* 19200 B */
#define NBLKQ 2048
#define NPAD 48
#define WB_ELEM_S (KS_ * NPAD * 32) /* 38400 */

typedef __attribute__((ext_vector_type(8))) short bf16x8;
typedef __attribute__((ext_vector_type(4))) float f32x4;
typedef __attribute__((ext_vector_type(4))) int i32x4;

__device__ __forceinline__ float waveReduceSum(float v) {
#pragma unroll
  for (int m = 32; m >= 1; m >>= 1) v += __shfl_xor(v, m, 64);
  return v;
}

__device__ __forceinline__ unsigned short f2bf(float f) {
  __hip_bfloat16 h = __float2bfloat16(f);
  return *reinterpret_cast<unsigned short*>(&h);
}

// W[s][n][c][j] fp32 -> WBg[s][j][n(48)][c(32)] bf16, zero-padded.
__global__ __launch_bounds__(192) void wconv_kernel(const float* __restrict__ W,
                                                    unsigned short* __restrict__ WBg) {
  const int s = blockIdx.x / KS_;
  const int j = blockIdx.x % KS_;
  const int n = threadIdx.x >> 2;
  const int q = threadIdx.x & 3;
  union {
    unsigned short u[8];
    i32x4 v;
  } pk;
#pragma unroll
  for (int e = 0; e < 8; ++e) {
    const int c = q * 8 + e;
    float v = 0.f;
    if (n < K_ && c < C_) v = W[(((size_t)s * K_ + n) * C_ + c) * KS_ + j];
    pk.u[e] = f2bf(v);
  }
  *(i32x4*)(WBg + ((size_t)(s * KS_ + j) * NPAD + n) * 32 + q * 8) = pk.v;
}

#define MFMA12(A, Bv)                                                          \
  do {                                                                         \
    _Pragma("unroll") for (int nt_ = 0; nt_ < 3; ++nt_) {                      \
      _Pragma("unroll") for (int m_ = 0; m_ < 4; ++m_) {                       \
        acc[m_][nt_] =                                                         \
            __builtin_amdgcn_mfma_f32_16x16x32_bf16(A[m_], Bv[nt_], acc[m_][nt_], 0, 0, 0); \
      }                                                                        \
    }                                                                          \
  } while (0)

#define LDA(J, A)                                                              \
  do {                                                                         \
    const int tl_ = tbl + (J);                                                 \
    const char* ap_ = sm + tl_ * 64 + ((lg ^ ((tl_ >> 1) & 3)) << 4);          \
    _Pragma("unroll") for (int m_ = 0; m_ < 4; ++m_) {                         \
      A[m_] = *(const bf16x8*)(ap_ + m_ * 1024);                               \
    }                                                                          \
  } while (0)

#define LDB(J, Bv)                                                             \
  do {                                                                         \
    const unsigned short* bp_ = WBs + (J) * 1536;                              \
    _Pragma("unroll") for (int nt_ = 0; nt_ < 3; ++nt_) {                      \
      Bv[nt_] = *(const bf16x8*)(bp_ + nt_ * 512);                             \
    }                                                                          \
  } while (0)

// 2048 blocks = (sample b, quarter p). 256 thr = 4 waves; wave wv owns output
// rows [p*256 + wv*64, +64). A from LDS (64B rows, XOR (t>>1)&3 swizzle —
// measured conflict-free). B straight from global (L2-hot 48KB/sid).
__global__ __launch_bounds__(256, 4) void conv_kernel(
    const float* __restrict__ x, const unsigned short* __restrict__ WBg,
    const float* __restrict__ bias, float* __restrict__ pooled,
    float* __restrict__ part_sum, float* __restrict__ part_sq) {
  extern __shared__ __align__(16) char sm[];
  const int blk = blockIdx.x;
  const int b = blk >> 2;
  const int p = blk & 3;
  const int rbg = p * 256;  // global output-row base of this piece
  const int tid = threadIdx.x;

  int s = (int)rintf(x[(size_t)b * (C_ * TIN) + (TIN - 1)] * 1e-6f) - 1;
  s = __builtin_amdgcn_readfirstlane(min(max(s, 0), 8));

  // ---- stage xT piece: transpose + bf16 + chunk-XOR swizzle; zero pad ----
  {
    const float* xb = x + (size_t)b * (C_ * TIN);
    for (int task = tid; task < 4 * QROWS; task += 256) {
      const int q = task / QROWS;        // physical 16B chunk
      const int tr = task - q * QROWS;   // local row (coalesced along tid)
      const int lq = q ^ ((tr >> 1) & 3);
      const int tg = rbg + tr;
      union {
        unsigned short u[8];
        i32x4 v;
      } pk;
#pragma unroll
      for (int e = 0; e < 8; ++e) {
        const int c = lq * 8 + e;
        float v = 0.f;
        if (c < C_ && tg < TIN - 1) v = xb[c * TIN + tg];
        pk.u[e] = f2bf(v);
      }
      *(i32x4*)(sm + tr * 64 + q * 16) = pk.v;
    }
  }
  __syncthreads();

  const int lane = tid & 63;
  const int wv = tid >> 6;
  const int l15 = lane & 15;
  const int lg = lane >> 4;
  const int tbl = wv * 64 + l15;  // local m=0 A-row for this lane

  const unsigned short* WBs = WBg + (size_t)s * WB_ELEM_S + (l15 * 32 + lg * 8);

  f32x4 acc[4][3];
#pragma unroll
  for (int m = 0; m < 4; ++m)
#pragma unroll
    for (int nt = 0; nt < 3; ++nt) acc[m][nt] = (f32x4){0.f, 0.f, 0.f, 0.f};

  bf16x8 A0[4], A1[4], B0[3], B1[3];

  LDA(0, A0);
  LDB(0, B0);
  for (int j = 0; j < 24; j += 2) {
    LDA(j + 1, A1);
    LDB(j + 1, B1);
    MFMA12(A0, B0);
    LDA(j + 2, A0);
    LDB(j + 2, B0);
    MFMA12(A1, B1);
  }
  MFMA12(A0, B0);  // j = 24

  // ---- epilogue: bias + ELU, BN partials, pooled-window partials ----
  float bv[3];
#pragma unroll
  for (int nt = 0; nt < 3; ++nt) {
    const int k = nt * 16 + l15;
    bv[nt] = bias[s * K_ + (k < K_ ? k : 0)];
  }
  const int wbase = rbg / P_;            // 0,2,5,7
  const int base100 = wbase * P_;
  float sY[3] = {0.f, 0.f, 0.f}, sY2[3] = {0.f, 0.f, 0.f};
  float pw[4][3];
#pragma unroll
  for (int w4 = 0; w4 < 4; ++w4)
#pragma unroll
    for (int nt = 0; nt < 3; ++nt) pw[w4][nt] = 0.f;

#pragma unroll
  for (int m = 0; m < 4; ++m) {
#pragma unroll
    for (int i = 0; i < 4; ++i) {
      const int t = rbg + wv * 64 + m * 16 + lg * 4 + i;
      const bool valid = (t < TO);
      const bool pool = (t < NW * P_);
      const int d = t - base100;
#pragma unroll
      for (int nt = 0; nt < 3; ++nt) {
        const float v = acc[m][nt][i] + bv[nt];
        const float y = v > 0.f ? v : expm1f(v);
        if (valid) {
          sY[nt] += y;
          sY2[nt] += y * y;
          if (pool) {
            if (d < P_)
              pw[0][nt] += y;
            else if (d < 2 * P_)
              pw[1][nt] += y;
            else if (d < 3 * P_)
              pw[2][nt] += y;
            else
              pw[3][nt] += y;
          }
        }
      }
    }
  }

  float* red = (float*)(sm + RED_OFF);
#pragma unroll
  for (int nt = 0; nt < 3; ++nt) {
#pragma unroll
    for (int r = 16; r <= 32; r <<= 1) {
      pw[0][nt] += __shfl_xor(pw[0][nt], r, 64);
      pw[1][nt] += __shfl_xor(pw[1][nt], r, 64);
      pw[2][nt] += __shfl_xor(pw[2][nt], r, 64);
      pw[3][nt] += __shfl_xor(pw[3][nt], r, 64);
      sY[nt] += __shfl_xor(sY[nt], r, 64);
      sY2[nt] += __shfl_xor(sY2[nt], r, 64);
    }
    const int k = nt * 16 + l15;
    if (lane < 16 && k < K_) {
      float* pb = pooled + (size_t)b * FCIN + k * NW;
#pragma unroll
      for (int w4 = 0; w4 < 4; ++w4) {
        const int wg = wbase + w4;
        if (wg <= NW - 1 && pw[w4][nt] != 0.f) atomicAdd(&pb[wg], pw[w4][nt]);
      }
      red[k * 4 + wv] = sY[nt];
      red[K_ * 4 + k * 4 + wv] = sY2[nt];
    }
  }
  __syncthreads();
  if (tid < K_) {
    float a = 0.f, q = 0.f;
#pragma unroll
    for (int i = 0; i < 4; ++i) {
      a += red[tid * 4 + i];
      q += red[K_ * 4 + tid * 4 + i];
    }
    part_sum[(size_t)tid * NBLKQ + blk] = a;
    part_sq[(size_t)tid * NBLKQ + blk] = q;
  }
}

__global__ __launch_bounds__(256) void stats_kernel(
    const float* __restrict__ part_sum, const float* __restrict__ part_sq,
    const float* __restrict__ gamma, const float* __restrict__ beta,
    float* __restrict__ ss) {
  const int k = blockIdx.x;
  float s = 0.f, q = 0.f;
  for (int i = threadIdx.x; i < NBLKQ; i += 256) {
    s += part_sum[(size_t)k * NBLKQ + i];
    q += part_sq[(size_t)k * NBLKQ + i];
  }
  s = waveReduceSum(s);
  q = waveReduceSum(q);
  __shared__ float ls[4], lq[4];
  const int wave = threadIdx.x >> 6, lane = threadIdx.x & 63;
  if (lane == 0) {
    ls[wave] = s;
    lq[wave] = q;
  }
  __syncthreads();
  if (threadIdx.x == 0) {
    const float S = ls[0] + ls[1] + ls[2] + ls[3];
    const float Q = lq[0] + lq[1] + lq[2] + lq[3];
    const float N = (float)B_ * (float)TO;
    const float mean = S / N;
    const float var = Q / N - mean * mean;
    const float sc = gamma[k] / sqrtf(var + 1e-5f);
    ss[k] = sc;
    ss[K_ + k] = beta[k] - mean * sc;
  }
}

__global__ __launch_bounds__(256) void fc_kernel(
    const float* __restrict__ pooled, const float* __restrict__ ss,
    const float* __restrict__ fc_w, const float* __restrict__ fc_b,
    float* __restrict__ out) {
  const int bb = blockIdx.x;
  const int n = threadIdx.x >> 6;
  const int lane = threadIdx.x & 63;
  float acc = 0.f;
  for (int i = lane; i < FCIN; i += 64) {
    const int k = i / NW;
    const float y = pooled[(size_t)bb * FCIN + i] * (1.f / (float)P_) * ss[k] + ss[K_ + k];
    acc = fmaf(y, fc_w[n * FCIN + i], acc);
  }
  acc = waveReduceSum(acc);
  if (lane == 0) out[bb * NOUT + n] = acc + fc_b[n];
}

extern "C" void kernel_launch(void* const* d_in, const int* in_sizes, int n_in,
                              void* d_out, int out_size, void* d_ws, size_t ws_size,
                              hipStream_t stream) {
  const float* x = (const float*)d_in[0];
  const float* W = (const float*)d_in[1];
  const float* bias = (const float*)d_in[2];
  const float* gamma = (const float*)d_in[3];
  const float* beta = (const float*)d_in[4];
  const float* fc_w = (const float*)d_in[5];
  const float* fc_b = (const float*)d_in[6];
  float* out = (float*)d_out;

  char* ws = (char*)d_ws;
  float* pooled = (float*)ws;                             // 737280 B
  float* part_sum = (float*)(ws + 737280);                // 40*2048*4 = 327680
  float* part_sq = (float*)(ws + 1064960);                // 327680
  unsigned short* WBg = (unsigned short*)(ws + 1392640);  // 691200
  float* ss = (float*)(ws + 2083840);                     // 320

  hipFuncSetAttribute((const void*)conv_kernel,
                      hipFuncAttributeMaxDynamicSharedMemorySize, LDS_TOTAL);

  hipMemsetAsync(pooled, 0, 737280, stream);
  wconv_kernel<<<9 * KS_, 192, 0, stream>>>(W, WBg);
  conv_kernel<<<NBLKQ, 256, LDS_TOTAL, stream>>>(x, WBg, bias, pooled, part_sum, part_sq);
  stats_kernel<<<K_, 256, 0, stream>>>(part_sum, part_sq, gamma, beta, ss);
  fc_kernel<<<B_, 256, 0, stream>>>(pooled, ss, fc_w, fc_b, out);
}